// Round 5
// baseline (155.413 us; speedup 1.0000x reference)
//
#include <hip/hip_runtime.h>

#define N_NODES 50000
#define N_EDGES 800000
#define IN_DIM 128
#define OUT_DIM 64
#define CAP 64            // max row degree ~35 (Binomial(800k,1/50k)), 64 is safe

// Block layout: GEMM blocks FIRST so they are co-resident with the bucket
// blocks (8 blocks/CU * 256 CU = 2048 resident).
#define GEMM_BLOCKS 784               // 784*4 waves = 3136 >= 3125 groups
#define EDGES_PER_BLOCK 512           // 2 edges/thread, 2 independent chains
#define BUCKET_BLOCKS ((N_EDGES + EDGES_PER_BLOCK - 1) / EDGES_PER_BLOCK)  // 1563
#define TOTAL_BLOCKS (GEMM_BLOCKS + BUCKET_BLOCKS)

// workspace layout (bytes), 16B-aligned
#define OFF_HID 0u          // bf16 hidden: 50000*64*2 = 6,400,000
#define OFF_DEG 6400000u    // int deg: 200,000
#define OFF_BKT 6600192u    // int2 bucket: 50000*64*8 = 25,600,000  (total ~32 MB)

typedef short short8 __attribute__((ext_vector_type(8)));
typedef float f32x4 __attribute__((ext_vector_type(4)));
typedef float f32x2 __attribute__((ext_vector_type(2)));

__device__ __forceinline__ unsigned short bf_rne(float f) {
    unsigned u = __float_as_uint(f);
    u += 0x7fffu + ((u >> 16) & 1u);   // round-to-nearest-even
    return (unsigned short)(u >> 16);
}
__device__ __forceinline__ float bf_lo(unsigned u) { return __uint_as_float(u << 16); }
__device__ __forceinline__ float bf_hi(unsigned u) { return __uint_as_float(u & 0xffff0000u); }

// ---------------------------------------------------------------------------
// FUSED kernel. blocks [0, 784): MFMA GEMM hidden = x @ w.
// blocks [784, 784+1563): SINGLE-PASS edge bucketing — each edge is read and
// processed exactly ONCE (previous XCD-partitioned scheme processed each edge
// 8x to filter by row range; counters showed the L2-locality payoff never
// materialized while the 8x issue/wave redundancy dominated the phase).
// ---------------------------------------------------------------------------
__global__ __launch_bounds__(256) void fused_kernel(
        const float* __restrict__ x, const float* __restrict__ w,
        unsigned short* __restrict__ hidb,
        const int* __restrict__ erow, const int* __restrict__ ecol,
        const float* __restrict__ eval,
        int* __restrict__ deg, int2* __restrict__ bucket) {
    if (blockIdx.x >= GEMM_BLOCKS) {
        const int bb = blockIdx.x - GEMM_BLOCKS;
        const int e0 = bb * EDGES_PER_BLOCK + threadIdx.x;
        const int eA = e0, eB = e0 + 256;
        // two independent load->atomic->store chains
        const bool aok = eA < N_EDGES;
        const bool bok = eB < N_EDGES;
        int rA = 0, cA = 0, rB = 0, cB = 0;
        float vA = 0.f, vB = 0.f;
        if (aok) { rA = erow[eA]; cA = ecol[eA]; vA = eval[eA]; }
        if (bok) { rB = erow[eB]; cB = ecol[eB]; vB = eval[eB]; }
        if (aok) {
            const int pos = atomicAdd(&deg[rA], 1);
            if (pos < CAP) bucket[(size_t)rA * CAP + pos] = make_int2(cA, __float_as_int(vA));
        }
        if (bok) {
            const int pos = atomicAdd(&deg[rB], 1);
            if (pos < CAP) bucket[(size_t)rB * CAP + pos] = make_int2(cB, __float_as_int(vB));
        }
        return;
    }

    // ---- GEMM path: hidden(bf16) = x @ w, one wave per 16-node group ----
    __shared__ __attribute__((aligned(16))) unsigned short smem[16 * 64 * 8];  // 16 KB

    const int tid = threadIdx.x;
    const int lane = tid & 63;
    const int wid = tid >> 6;

    // stage w into B-fragment order — coalesced float4 global reads,
    // scattered cheap LDS u16 writes.
    #pragma unroll
    for (int it = 0; it < 8; ++it) {
        const int e = it * 1024 + tid * 4;
        const f32x4 wv = *(const f32x4*)(w + e);
        const int k = e >> 6;
        const int n0 = e & 63;
        const int c = k >> 5, j = k & 7, lhi = ((k >> 3) & 3) * 16;
        #pragma unroll
        for (int m = 0; m < 4; ++m) {
            const int n = n0 + m;
            const int t = n >> 4;
            const int ln = lhi + (n & 15);
            smem[((c * 4 + t) * 64 + ln) * 8 + j] = bf_rne(wv[m]);
        }
    }
    __syncthreads();

    const int group = blockIdx.x * 4 + wid;   // 16-node group id

    short8 bf[16];
    if (group < N_NODES / 16) {
        #pragma unroll
        for (int f = 0; f < 16; ++f)
            bf[f] = *(const short8*)&smem[(f * 64 + lane) * 8];
    }
    __syncthreads();   // all waves have frags in regs -> smem reusable

    if (group < N_NODES / 16) {
        const int node0 = group * 16;
        f32x4 acc[4] = {{0, 0, 0, 0}, {0, 0, 0, 0}, {0, 0, 0, 0}, {0, 0, 0, 0}};

        #pragma unroll
        for (int c = 0; c < 4; ++c) {
            const float* xr = x + (size_t)(node0 + (lane & 15)) * IN_DIM + c * 32 + (lane >> 4) * 8;
            const float4 a0 = *(const float4*)xr;
            const float4 a1 = *(const float4*)(xr + 4);
            short8 af;
            af[0] = (short)bf_rne(a0.x); af[1] = (short)bf_rne(a0.y);
            af[2] = (short)bf_rne(a0.z); af[3] = (short)bf_rne(a0.w);
            af[4] = (short)bf_rne(a1.x); af[5] = (short)bf_rne(a1.y);
            af[6] = (short)bf_rne(a1.z); af[7] = (short)bf_rne(a1.w);
            #pragma unroll
            for (int t = 0; t < 4; ++t)
                acc[t] = __builtin_amdgcn_mfma_f32_16x16x32_bf16(af, bf[c * 4 + t], acc[t], 0, 0, 0);
        }

        // epilogue: D[m][n] -> smem bounce (wave-private slice) -> global
        // hidb stores stay cached: agg re-reads each row ~16x.
        unsigned short* obuf = smem + wid * 1024;
        #pragma unroll
        for (int t = 0; t < 4; ++t)
            #pragma unroll
            for (int r = 0; r < 4; ++r)
                obuf[((lane >> 4) * 4 + r) * 64 + t * 16 + (lane & 15)] = bf_rne(acc[t][r]);
        const uint4 o0 = *(const uint4*)&obuf[lane * 16];
        const uint4 o1 = *(const uint4*)&obuf[lane * 16 + 8];
        char* dst = (char*)hidb + (size_t)node0 * (OUT_DIM * 2) + lane * 32;
        *(uint4*)dst = o0;
        *(uint4*)(dst + 16) = o1;
    }
}

// ---------------------------------------------------------------------------
// Aggregate: 4 rows per wave (quarter q = row, 16 lanes x 8 B cover the
// 128-B hidden row). Edge (col,val) staged to registers once (nt loads —
// one-shot data), broadcast via __shfl; gathers batched 8-deep before fmas.
// out stores non-temporal (never re-read).
// ---------------------------------------------------------------------------
__device__ __forceinline__ void proc8(const unsigned short* __restrict__ hidb,
                                      int2 P, int base, int eoff,
                                      int q, int l, int d, float4& acc) {
    unsigned long long u[8];
    float vv[8];
    #pragma unroll
    for (int e = 0; e < 8; ++e) {
        const int src = q * 16 + eoff + e;
        int c = __shfl(P.x, src);
        const int vi = __shfl(P.y, src);
        const bool act = (base + eoff + e) < d;
        c = act ? c : 0;
        vv[e] = act ? __int_as_float(vi) : 0.f;
        u[e] = *(const unsigned long long*)&hidb[(size_t)c * OUT_DIM + 4 * l];
    }
    #pragma unroll
    for (int e = 0; e < 8; ++e) {
        const float v = vv[e];
        const unsigned ulo = (unsigned)u[e];
        const unsigned uhi = (unsigned)(u[e] >> 32);
        acc.x = fmaf(v, bf_lo(ulo), acc.x);
        acc.y = fmaf(v, bf_hi(ulo), acc.y);
        acc.z = fmaf(v, bf_lo(uhi), acc.z);
        acc.w = fmaf(v, bf_hi(uhi), acc.w);
    }
}

__device__ __forceinline__ int2 nt_int2(const int2* p) {
    const unsigned long long v = __builtin_nontemporal_load((const unsigned long long*)p);
    return make_int2((int)(unsigned)v, (int)(unsigned)(v >> 32));
}

__global__ __launch_bounds__(256) void agg_kernel(const unsigned short* __restrict__ hidb,
                                                  const int* __restrict__ deg,
                                                  const int2* __restrict__ bucket,
                                                  const float* __restrict__ b,
                                                  float* __restrict__ out) {
    const int tid = threadIdx.x;
    const int lane = tid & 63;
    const int wid = tid >> 6;
    const int q = lane >> 4;        // quarter = which of the wave's 4 rows
    const int l = lane & 15;        // dims 4l .. 4l+3
    const int row = blockIdx.x * 16 + wid * 4 + q;   // grid covers exactly 50000

    const int d = min(deg[row], CAP);
    const int2* __restrict__ ep = bucket + (size_t)row * CAP;

    // wave-uniform max degree over the 4 quarters (uniform loop trip counts)
    int dmax = d;
    dmax = max(dmax, __shfl_xor(dmax, 16));
    dmax = max(dmax, __shfl_xor(dmax, 32));

    // stage first 32 edge slots to registers; beyond-deg entries gated off
    const int2 pa = nt_int2(&ep[l]);
    const int2 pb = nt_int2(&ep[16 + l]);

    float4 acc = make_float4(0.f, 0.f, 0.f, 0.f);

    proc8(hidb, pa, 0, 0, q, l, d, acc);
    if (dmax > 8)  proc8(hidb, pa, 0, 8, q, l, d, acc);
    if (dmax > 16) proc8(hidb, pb, 16, 0, q, l, d, acc);
    if (dmax > 24) proc8(hidb, pb, 16, 8, q, l, d, acc);
    for (int base = 32; base < dmax; base += 16) {     // rare tail
        const int2 pc = nt_int2(&ep[base + l]);
        proc8(hidb, pc, base, 0, q, l, d, acc);
        if (dmax > base + 8) proc8(hidb, pc, base, 8, q, l, d, acc);
    }

    const float2 bbv = *(const float2*)&b[4 * l];     // b is tiny, cached
    const float2 bbv2 = *(const float2*)&b[4 * l + 2];
    f32x2 o0, o1;
    o0[0] = fmaxf(acc.x + bbv.x, 0.f);
    o0[1] = fmaxf(acc.y + bbv.y, 0.f);
    o1[0] = fmaxf(acc.z + bbv2.x, 0.f);
    o1[1] = fmaxf(acc.w + bbv2.y, 0.f);
    float* dst = out + (size_t)row * OUT_DIM + 4 * l;
    __builtin_nontemporal_store(o0, (f32x2*)dst);
    __builtin_nontemporal_store(o1, (f32x2*)(dst + 2));
}

extern "C" void kernel_launch(void* const* d_in, const int* in_sizes, int n_in,
                              void* d_out, int out_size, void* d_ws, size_t ws_size,
                              hipStream_t stream) {
    const float* x    = (const float*)d_in[0];
    const int*   erow = (const int*)d_in[1];
    const int*   ecol = (const int*)d_in[2];
    const float* eval = (const float*)d_in[3];
    const float* w    = (const float*)d_in[4];
    const float* b    = (const float*)d_in[5];
    float* out = (float*)d_out;

    char* ws = (char*)d_ws;
    unsigned short* hidb = (unsigned short*)(ws + OFF_HID);
    int*  deg    = (int*)(ws + OFF_DEG);
    int2* bucket = (int2*)(ws + OFF_BKT);

    hipMemsetAsync(deg, 0, N_NODES * sizeof(int), stream);

    // 1) fused: GEMM (blocks 0..783) overlapped with single-pass bucket
    fused_kernel<<<TOTAL_BLOCKS, 256, 0, stream>>>(
        x, w, hidb, erow, ecol, eval, deg, bucket);

    // 2) per-row gather-accumulate (4 rows/wave, 8-B gathers), fused bias+relu
    agg_kernel<<<N_NODES / 16, 256, 0, stream>>>(hidb, deg, bucket, b, out);
}

// Round 6
// 142.948 us; speedup vs baseline: 1.0872x; 1.0872x over previous
//
#include <hip/hip_runtime.h>

#define N_NODES 50000
#define N_EDGES 800000
#define IN_DIM 128
#define OUT_DIM 64
#define CAP 64            // max row degree ~35 (Binomial(800k,1/50k), mean 16), 64 is safe
#define PARTS 8           // row partitions == XCD count
#define ROWS_PER_PART 6250
#define EDGES_PER_CHUNK 3125   // 800000 / 256 chunks

// Block layout: GEMM blocks FIRST so they are co-resident with the bucket
// blocks (8 blocks/CU * 256 CU = 2048 resident). 784%8==0 keeps the bucket
// blocks' blockIdx%8 == XCD mapping intact.
#define GEMM_BLOCKS 784               // 784*4 waves = 3136 >= 3125 groups
#define BUCKET_BLOCKS (256 * PARTS)   // 2048
#define TOTAL_BLOCKS (GEMM_BLOCKS + BUCKET_BLOCKS)

// workspace layout (bytes), 16B-aligned
#define OFF_HID 0u          // bf16 hidden: 50000*64*2 = 6,400,000
#define OFF_DEG 6400000u    // int deg: 200,000
#define OFF_BKT 6600192u    // int2 bucket: 50000*64*8 = 25,600,000  (total ~32 MB)

typedef short short8 __attribute__((ext_vector_type(8)));
typedef float f32x4 __attribute__((ext_vector_type(4)));

__device__ __forceinline__ unsigned short bf_rne(float f) {
    unsigned u = __float_as_uint(f);
    u += 0x7fffu + ((u >> 16) & 1u);   // round-to-nearest-even
    return (unsigned short)(u >> 16);
}
__device__ __forceinline__ float bf_lo(unsigned u) { return __uint_as_float(u << 16); }
__device__ __forceinline__ float bf_hi(unsigned u) { return __uint_as_float(u & 0xffff0000u); }

// ---------------------------------------------------------------------------
// FUSED kernel (round-3 best form — XCD write locality is ESSENTIAL: removing
// it in R5 raised bucket write amplification 5x->7x and cost +20 us).
// blocks [0, 784): MFMA GEMM hidden = x @ w.
// blocks [784, 2832): edge bucketing, XCD-partitioned (part = bb&7 == XCD).
// Each partition re-reads the full edge list (8x redundancy, L3-absorbed) but
// writes ONLY its own 3.2 MB bucket section -> partial 64-B lines merge in
// the home XCD's L2 instead of false-sharing across 8 non-coherent L2s.
// 4-deep independent atomic->store chains cut serial latency exposure.
// NO non-temporal loads anywhere: R4 measured them as a 5 us regression.
// ---------------------------------------------------------------------------
__global__ __launch_bounds__(256) void fused_kernel(
        const float* __restrict__ x, const float* __restrict__ w,
        unsigned short* __restrict__ hidb,
        const int* __restrict__ erow, const int* __restrict__ ecol,
        const float* __restrict__ eval,
        int* __restrict__ deg, int2* __restrict__ bucket) {
    if (blockIdx.x >= GEMM_BLOCKS) {
        const int bb = blockIdx.x - GEMM_BLOCKS;
        const int part = bb & (PARTS - 1);           // == XCD id
        const int chunk = bb >> 3;
        const int rlo = part * ROWS_PER_PART;
        const int e0 = chunk * EDGES_PER_CHUNK;
        int i = threadIdx.x;
        // 3 full quad-trips: max index tid+2048+768 = 3071 < 3125
        #pragma unroll 1
        for (int trip = 0; trip < 3; ++trip, i += 1024) {
            const int eA = e0 + i,        eB = e0 + i + 256;
            const int eC = e0 + i + 512,  eD = e0 + i + 768;
            const int rA = erow[eA], rB = erow[eB], rC = erow[eC], rD = erow[eD];
            const int cA = ecol[eA], cB = ecol[eB], cC = ecol[eC], cD = ecol[eD];
            const float vA = eval[eA], vB = eval[eB], vC = eval[eC], vD = eval[eD];
            if ((unsigned)(rA - rlo) < (unsigned)ROWS_PER_PART) {
                const int pos = atomicAdd(&deg[rA], 1);
                if (pos < CAP) bucket[(size_t)rA * CAP + pos] = make_int2(cA, __float_as_int(vA));
            }
            if ((unsigned)(rB - rlo) < (unsigned)ROWS_PER_PART) {
                const int pos = atomicAdd(&deg[rB], 1);
                if (pos < CAP) bucket[(size_t)rB * CAP + pos] = make_int2(cB, __float_as_int(vB));
            }
            if ((unsigned)(rC - rlo) < (unsigned)ROWS_PER_PART) {
                const int pos = atomicAdd(&deg[rC], 1);
                if (pos < CAP) bucket[(size_t)rC * CAP + pos] = make_int2(cC, __float_as_int(vC));
            }
            if ((unsigned)(rD - rlo) < (unsigned)ROWS_PER_PART) {
                const int pos = atomicAdd(&deg[rD], 1);
                if (pos < CAP) bucket[(size_t)rD * CAP + pos] = make_int2(cD, __float_as_int(vD));
            }
        }
        if (i < EDGES_PER_CHUNK) {    // 53-slot tail (tid < 53)
            const int r = erow[e0 + i];
            const int c = ecol[e0 + i];
            const float v = eval[e0 + i];
            if ((unsigned)(r - rlo) < (unsigned)ROWS_PER_PART) {
                const int pos = atomicAdd(&deg[r], 1);
                if (pos < CAP) bucket[(size_t)r * CAP + pos] = make_int2(c, __float_as_int(v));
            }
        }
        return;
    }

    // ---- GEMM path: hidden(bf16) = x @ w, one wave per 16-node group ----
    __shared__ __attribute__((aligned(16))) unsigned short smem[16 * 64 * 8];  // 16 KB

    const int tid = threadIdx.x;
    const int lane = tid & 63;
    const int wid = tid >> 6;

    // stage w into B-fragment order — coalesced float4 global reads,
    // scattered cheap LDS u16 writes.
    #pragma unroll
    for (int it = 0; it < 8; ++it) {
        const int e = it * 1024 + tid * 4;
        const f32x4 wv = *(const f32x4*)(w + e);
        const int k = e >> 6;
        const int n0 = e & 63;
        const int c = k >> 5, j = k & 7, lhi = ((k >> 3) & 3) * 16;
        #pragma unroll
        for (int m = 0; m < 4; ++m) {
            const int n = n0 + m;
            const int t = n >> 4;
            const int ln = lhi + (n & 15);
            smem[((c * 4 + t) * 64 + ln) * 8 + j] = bf_rne(wv[m]);
        }
    }
    __syncthreads();

    const int group = blockIdx.x * 4 + wid;   // 16-node group id

    short8 bf[16];
    if (group < N_NODES / 16) {
        #pragma unroll
        for (int f = 0; f < 16; ++f)
            bf[f] = *(const short8*)&smem[(f * 64 + lane) * 8];
    }
    __syncthreads();   // all waves have frags in regs -> smem reusable

    if (group < N_NODES / 16) {
        const int node0 = group * 16;
        f32x4 acc[4] = {{0, 0, 0, 0}, {0, 0, 0, 0}, {0, 0, 0, 0}, {0, 0, 0, 0}};

        #pragma unroll
        for (int c = 0; c < 4; ++c) {
            const float* xr = x + (size_t)(node0 + (lane & 15)) * IN_DIM + c * 32 + (lane >> 4) * 8;
            const float4 a0 = *(const float4*)xr;
            const float4 a1 = *(const float4*)(xr + 4);
            short8 af;
            af[0] = (short)bf_rne(a0.x); af[1] = (short)bf_rne(a0.y);
            af[2] = (short)bf_rne(a0.z); af[3] = (short)bf_rne(a0.w);
            af[4] = (short)bf_rne(a1.x); af[5] = (short)bf_rne(a1.y);
            af[6] = (short)bf_rne(a1.z); af[7] = (short)bf_rne(a1.w);
            #pragma unroll
            for (int t = 0; t < 4; ++t)
                acc[t] = __builtin_amdgcn_mfma_f32_16x16x32_bf16(af, bf[c * 4 + t], acc[t], 0, 0, 0);
        }

        // epilogue: D[m][n] -> smem bounce (wave-private slice) -> global
        // hidb stores stay cached: agg re-reads each row ~16x.
        unsigned short* obuf = smem + wid * 1024;
        #pragma unroll
        for (int t = 0; t < 4; ++t)
            #pragma unroll
            for (int r = 0; r < 4; ++r)
                obuf[((lane >> 4) * 4 + r) * 64 + t * 16 + (lane & 15)] = bf_rne(acc[t][r]);
        const uint4 o0 = *(const uint4*)&obuf[lane * 16];
        const uint4 o1 = *(const uint4*)&obuf[lane * 16 + 8];
        char* dst = (char*)hidb + (size_t)node0 * (OUT_DIM * 2) + lane * 32;
        *(uint4*)dst = o0;
        *(uint4*)(dst + 16) = o1;
    }
}

// ---------------------------------------------------------------------------
// Aggregate: 4 rows per wave (quarter q = row, 16 lanes x 8 B cover the 128-B
// hidden row). All loads CACHED (bucket/deg are L2-hot from fused; nt cost
// 3.6 us in R4). MLP restructure vs R2: gathers issued in 16-deep windows —
// window 1 (slots 0-15) is UNCONDITIONAL straight-line code (mean deg = 16),
// window 2 (slots 16-31) under a single wave-uniform branch, rare tail after.
// This halves the branch/waitcnt serialization points and doubles loads in
// flight vs the old 8-deep guarded batches.
// ---------------------------------------------------------------------------
__device__ __forceinline__ void proc16(const unsigned short* __restrict__ hidb,
                                       int2 P, int base,
                                       int q, int l, int d, float4& acc) {
    unsigned long long u[16];
    float vv[16];
    #pragma unroll
    for (int e = 0; e < 16; ++e) {
        const int src = q * 16 + e;          // lane holding slot (base+e) of row q
        int c = __shfl(P.x, src);
        const int vi = __shfl(P.y, src);
        const bool act = (base + e) < d;
        c = act ? c : 0;
        vv[e] = act ? __int_as_float(vi) : 0.f;
        u[e] = *(const unsigned long long*)&hidb[(size_t)c * OUT_DIM + 4 * l];
    }
    #pragma unroll
    for (int e = 0; e < 16; ++e) {
        const float v = vv[e];
        const unsigned ulo = (unsigned)u[e];
        const unsigned uhi = (unsigned)(u[e] >> 32);
        acc.x = fmaf(v, bf_lo(ulo), acc.x);
        acc.y = fmaf(v, bf_hi(ulo), acc.y);
        acc.z = fmaf(v, bf_lo(uhi), acc.z);
        acc.w = fmaf(v, bf_hi(uhi), acc.w);
    }
}

__global__ __launch_bounds__(256) void agg_kernel(const unsigned short* __restrict__ hidb,
                                                  const int* __restrict__ deg,
                                                  const int2* __restrict__ bucket,
                                                  const float* __restrict__ b,
                                                  float* __restrict__ out) {
    const int tid = threadIdx.x;
    const int lane = tid & 63;
    const int wid = tid >> 6;
    const int q = lane >> 4;        // quarter = which of the wave's 4 rows
    const int l = lane & 15;        // dims 4l .. 4l+3
    const int row = blockIdx.x * 16 + wid * 4 + q;   // grid covers exactly 50000

    const int d = min(deg[row], CAP);
    const int2* __restrict__ ep = bucket + (size_t)row * CAP;

    // wave-uniform max degree over the 4 quarters (uniform trip counts)
    int dmax = d;
    dmax = max(dmax, __shfl_xor(dmax, 16));
    dmax = max(dmax, __shfl_xor(dmax, 32));

    // stage first 32 edge slots to registers; beyond-deg entries gated off
    const int2 pa = ep[l];
    const int2 pb = ep[16 + l];

    float4 acc = make_float4(0.f, 0.f, 0.f, 0.f);

    proc16(hidb, pa, 0, q, l, d, acc);                  // unconditional window
    if (dmax > 16) proc16(hidb, pb, 16, q, l, d, acc);  // one guarded window
    for (int base = 32; base < dmax; base += 16) {      // rare tail (P ~ 1e-4)
        const int2 pc = ep[base + l];
        proc16(hidb, pc, base, q, l, d, acc);
    }

    const float4 bb = *(const float4*)&b[4 * l];
    float4 o;
    o.x = fmaxf(acc.x + bb.x, 0.f);
    o.y = fmaxf(acc.y + bb.y, 0.f);
    o.z = fmaxf(acc.z + bb.z, 0.f);
    o.w = fmaxf(acc.w + bb.w, 0.f);
    *(float4*)&out[(size_t)row * OUT_DIM + 4 * l] = o;
}

extern "C" void kernel_launch(void* const* d_in, const int* in_sizes, int n_in,
                              void* d_out, int out_size, void* d_ws, size_t ws_size,
                              hipStream_t stream) {
    const float* x    = (const float*)d_in[0];
    const int*   erow = (const int*)d_in[1];
    const int*   ecol = (const int*)d_in[2];
    const float* eval = (const float*)d_in[3];
    const float* w    = (const float*)d_in[4];
    const float* b    = (const float*)d_in[5];
    float* out = (float*)d_out;

    char* ws = (char*)d_ws;
    unsigned short* hidb = (unsigned short*)(ws + OFF_HID);
    int*  deg    = (int*)(ws + OFF_DEG);
    int2* bucket = (int2*)(ws + OFF_BKT);

    hipMemsetAsync(deg, 0, N_NODES * sizeof(int), stream);

    // 1) fused: GEMM (blocks 0..783) overlapped with XCD-partitioned bucket
    fused_kernel<<<TOTAL_BLOCKS, 256, 0, stream>>>(
        x, w, hidb, erow, ecol, eval, deg, bucket);

    // 2) per-row gather-accumulate (4 rows/wave, 16-deep gather windows)
    agg_kernel<<<N_NODES / 16, 256, 0, stream>>>(hidb, deg, bucket, b, out);
}